// Round 9
// baseline (208.919 us; speedup 1.0000x reference)
//
#include <hip/hip_runtime.h>
#include <math.h>

#define IMG 256
#define NPIX (IMG*IMG)
#define SIGMA_INV 100.0f
#define EPSF 1e-6f
#define LOG2E 1.4426950408889634f
#define TANV 0.5773502691896258f   // tan(30 deg)
#define TSKIP 24.0f
#define FMAX 1024                  // F = 1000
#define NCHUNK 4
#define NTILE 1024                 // 32x32 tiles of 8x8 px
#define NSBLK (NTILE*NCHUNK)       // 4096 sil blocks

__device__ __forceinline__ float fexp2(float x) {
#if __has_builtin(__builtin_amdgcn_exp2f)
  return __builtin_amdgcn_exp2f(x);
#else
  return exp2f(x);
#endif
}
__device__ __forceinline__ float frcp(float x) {
#if __has_builtin(__builtin_amdgcn_rcpf)
  return __builtin_amdgcn_rcpf(x);
#else
  return 1.0f / x;
#endif
}
__device__ __forceinline__ float rlane(float x, int j) {
#if __has_builtin(__builtin_amdgcn_readlane)
  return __int_as_float(__builtin_amdgcn_readlane(__float_as_int(x), j));
#else
  return __shfl(x, j);
#endif
}

// Contraction-off cross product (sign(area) of non-degenerate faces).
__device__ __forceinline__ float cross2(float ax, float ay, float bx, float by) {
#pragma clang fp contract(off)
  return ax * by - ay * bx;
}

// Prep: ONE thread per face, computed ONCE (R8 showed per-block inline prep
// costs ~7us in aggregate redundancy). SoA edge constants:
// t_k(p) = px*A.x + py*A.y + A.z ; frag = 1/((1+2^t0)(1+2^t1)(1+2^t2)).
// Faces with a repeated vertex INDEX get s=0 exactly (matches numpy's
// exact-zero area -> sign=0 -> frag=1/8 everywhere; dominates the loss).
__global__ void prep_kernel(const float* __restrict__ verts,
                            const int* __restrict__ faces,
                            const float* __restrict__ cam,
                            float4* __restrict__ fd0, float4* __restrict__ fd1,
                            float4* __restrict__ fd2, int F) {
  int f = blockIdx.x * blockDim.x + threadIdx.x;
  if (f >= F) return;
  float ex = cam[0], ey = cam[1], ez = cam[2];
  float zn = sqrtf(ex * ex + ey * ey + ez * ez) + EPSF;
  float izn = frcp(zn);
  float zx = -ex * izn, zy = -ey * izn, zz = -ez * izn;
  float xn = sqrtf(zz * zz + zx * zx) + EPSF;
  float ixn = frcp(xn);
  float xx = zz * ixn, xz = -zx * ixn;           // xy = 0
  float yx = zy * xz;                            // cross(z,x) with xy=0
  float yy = zz * xx - zx * xz;
  float yz = -zy * xx;

  int i0 = faces[3 * f + 0], i1 = faces[3 * f + 1], i2 = faces[3 * f + 2];
  bool deg = (i0 == i1) | (i1 == i2) | (i0 == i2);
  int vi_[3] = {i0, i1, i2};

  float pxs[3], pys[3];
#pragma unroll
  for (int k = 0; k < 3; ++k) {
    int vi = vi_[k];
    float ax = verts[3 * vi + 0] - ex;
    float ay = verts[3 * vi + 1] - ey;
    float az = verts[3 * vi + 2] - ez;
    float vx = ax * xx + az * xz;
    float vy = ax * yx + ay * yy + az * yz;
    float vz = ax * zx + ay * zy + az * zz;
    float izw = frcp(vz * TANV);
    pxs[k] = vx * izw;
    pys[k] = vy * izw;
  }
  float e01x = pxs[1] - pxs[0], e01y = pys[1] - pys[0];
  float e02x = pxs[2] - pxs[0], e02y = pys[2] - pys[0];
  float area = cross2(e01x, e01y, e02x, e02y);
  float s = deg ? 0.0f
                : ((area > 0.0f) ? 1.0f : ((area < 0.0f) ? -1.0f : 0.0f));
  float K = -s * SIGMA_INV * LOG2E;
  float4 o[3];
#pragma unroll
  for (int k = 0; k < 3; ++k) {
    int kn = (k == 2) ? 0 : k + 1;
    float dx = pxs[kn] - pxs[k], dy = pys[kn] - pys[k];
    float il = frcp(sqrtf(dx * dx + dy * dy) + EPSF);
    float nx = -dy * il, ny = dx * il;
    float c = pxs[k] * nx + pys[k] * ny;
    o[k] = make_float4(nx * K, ny * K, -c * K, 0.0f);
  }
  fd0[f] = o[0]; fd1[f] = o[1]; fd2[f] = o[2];
}

// Silhouette + fused loss. Block = (tile, chunk) from swizzled blockIdx;
// 4 waves x 64 faces cover the 250-face chunk (all 64 lanes active in the
// relevance scan). After the block writes its chunk's 64-px partial product,
// it increments tile_done[tile]; the LAST arriver combines the 4 layers,
// computes (sil-ref)^2, wave-reduces, atomicAdds into accum; the last tile
// completer writes out[0]. No spinning; device-scope fences for cross-XCD
// visibility of part[] (split-K semaphore pattern).
__global__ __launch_bounds__(256) void sil_kernel(
    const float4* __restrict__ fd0, const float4* __restrict__ fd1,
    const float4* __restrict__ fd2, const float* __restrict__ ref,
    float* part, unsigned int* tile_done, float* accum,
    unsigned int* done_tiles, float* out, int F, int cpf) {
  __shared__ float s_part[NCHUNK * 64];
  __shared__ unsigned int s_old;

  int q = (blockIdx.x * 1637) & (NSBLK - 1);   // odd mult: bijection mod 4096
  int tile = q >> 2, chunk = q & 3;
  int tid = threadIdx.x;
  int lane = tid & 63, w = tid >> 6;
  int bx = tile & 31, by = tile >> 5;
  int ix = (bx << 3) + (lane & 7);
  int iy = (by << 3) + (lane >> 3);
  int pix = iy * IMG + ix;
  float px = (2.0f * (float)ix + 1.0f) * (1.0f / IMG) - 1.0f;
  float py = 1.0f - (2.0f * (float)iy + 1.0f) * (1.0f / IMG);
  float cx = ((float)(16 * bx + 8)) * (1.0f / IMG) - 1.0f;
  float cy = 1.0f - ((float)(16 * by + 8)) * (1.0f / IMG);
  const float h = 7.0f / IMG;                  // tile half-extent (centers)

  // this wave's 64-face batch within the chunk
  int r = w * 64 + lane;                       // 0..255 within chunk
  int f = chunk * cpf + r;
  int idx = (f < F) ? f : F - 1;               // clamped for safe loads
  float4 a0 = fd0[idx];
  float4 a1 = fd1[idx];
  float4 a2 = fd2[idx];
  // conservative min over tile of t_k; skip face iff some edge >= TSKIP
  float m0 = fmaf(cx, a0.x, fmaf(cy, a0.y, a0.z)) - (fabsf(a0.x) + fabsf(a0.y)) * h;
  float m1 = fmaf(cx, a1.x, fmaf(cy, a1.y, a1.z)) - (fabsf(a1.x) + fabsf(a1.y)) * h;
  float m2 = fmaf(cx, a2.x, fmaf(cy, a2.y, a2.z)) - (fabsf(a2.x) + fabsf(a2.y)) * h;
  bool rel = (r < cpf) && (f < F) && (fmaxf(m0, fmaxf(m1, m2)) < TSKIP);
  unsigned long long mask = __ballot(rel ? 1 : 0);

  float acc = 1.0f;
  while (mask) {
    int j = __builtin_ctzll(mask);
    mask &= mask - 1;
    // broadcast face j's 9 constants from lane j's registers (no memory)
    float b0x = rlane(a0.x, j), b0y = rlane(a0.y, j), b0z = rlane(a0.z, j);
    float b1x = rlane(a1.x, j), b1y = rlane(a1.y, j), b1z = rlane(a1.z, j);
    float b2x = rlane(a2.x, j), b2y = rlane(a2.y, j), b2z = rlane(a2.z, j);
    float t0 = fmaf(px, b0x, fmaf(py, b0y, b0z));
    float t1 = fmaf(px, b1x, fmaf(py, b1y, b1z));
    float t2 = fmaf(px, b2x, fmaf(py, b2y, b2z));
    float D = (1.0f + fexp2(t0)) * (1.0f + fexp2(t1)) * (1.0f + fexp2(t2));
    acc = fmaf(-frcp(D), acc, acc);            // acc *= 1 - 1/D
  }

  s_part[w * 64 + lane] = acc;
  __syncthreads();

  if (w == 0) {
    float p = s_part[lane] * s_part[64 + lane] *
              s_part[128 + lane] * s_part[192 + lane];
    part[chunk * NPIX + pix] = p;
    __threadfence();                           // release: part visible device-wide
    if (lane == 0) s_old = atomicAdd(&tile_done[tile], 1u);
  }
  __syncthreads();

  if (w == 0 && s_old == NCHUNK - 1) {
    __threadfence();                           // acquire: see others' part
    float a = part[pix] * part[pix + NPIX] *
              part[pix + 2 * NPIX] * part[pix + 3 * NPIX];
    float d = (1.0f - a) - ref[pix];
    float v = d * d;
#pragma unroll
    for (int off = 32; off > 0; off >>= 1) v += __shfl_down(v, off);
    if (lane == 0) {
      atomicAdd(accum, v);
      __threadfence();
      unsigned int t = atomicAdd(done_tiles, 1u);
      if (t == NTILE - 1) {
        __threadfence();
        out[0] = atomicAdd(accum, 0.0f);       // coherent read of final sum
      }
    }
  }
}

extern "C" void kernel_launch(void* const* d_in, const int* in_sizes, int n_in,
                              void* d_out, int out_size, void* d_ws, size_t ws_size,
                              hipStream_t stream) {
  const float* verts = (const float*)d_in[0];
  const int* faces = (const int*)d_in[1];
  const float* cam = (const float*)d_in[2];
  const float* imref = (const float*)d_in[3];
  int V = in_sizes[0] / 3;  (void)V;
  int F = in_sizes[1] / 3;  // 1000
  float* out = (float*)d_out;

  char* ws = (char*)d_ws;
  // [0,8K): counters -- accum, done_tiles, tile_done[1024]
  float* accum = (float*)ws;
  unsigned int* done_tiles = (unsigned int*)(ws + 4);
  unsigned int* tile_done = (unsigned int*)(ws + 8);
  float4* fd0 = (float4*)(ws + 8192);
  float4* fd1 = (float4*)(ws + 8192 + FMAX * 16);
  float4* fd2 = (float4*)(ws + 8192 + 2 * FMAX * 16);
  float* part = (float*)(ws + 65536);          // NCHUNK * NPIX floats (1 MB)

  hipMemsetAsync(ws, 0, 8 + NTILE * 4, stream);
  prep_kernel<<<(F + 255) / 256, 256, 0, stream>>>(verts, faces, cam,
                                                   fd0, fd1, fd2, F);
  int cpf = (F + NCHUNK - 1) / NCHUNK;         // 250
  sil_kernel<<<NSBLK, 256, 0, stream>>>(fd0, fd1, fd2, imref, part,
                                        tile_done, accum, done_tiles, out,
                                        F, cpf);
}

// Round 10
// 83.836 us; speedup vs baseline: 2.4920x; 2.4920x over previous
//
#include <hip/hip_runtime.h>
#include <math.h>

#define IMG 256
#define NPIX (IMG*IMG)
#define SIGMA_INV 100.0f
#define EPSF 1e-6f
#define LOG2E 1.4426950408889634f
#define TANV 0.5773502691896258f   // tan(30 deg)
#define TSKIP 24.0f
#define FMAX 1024                  // F = 1000
#define NCHUNK 4
#define NTILE 1024                 // 32x32 tiles of 8x8 px
#define NSBLK (NTILE*NCHUNK)       // 4096 sil blocks
#define NLBLK 128                  // loss blocks (128*512 = NPIX)

__device__ __forceinline__ float fexp2(float x) {
#if __has_builtin(__builtin_amdgcn_exp2f)
  return __builtin_amdgcn_exp2f(x);
#else
  return exp2f(x);
#endif
}
__device__ __forceinline__ float frcp(float x) {
#if __has_builtin(__builtin_amdgcn_rcpf)
  return __builtin_amdgcn_rcpf(x);
#else
  return 1.0f / x;
#endif
}
__device__ __forceinline__ float rlane(float x, int j) {
#if __has_builtin(__builtin_amdgcn_readlane)
  return __int_as_float(__builtin_amdgcn_readlane(__float_as_int(x), j));
#else
  return __shfl(x, j);
#endif
}

// Contraction-off cross product (sign(area) of non-degenerate faces).
__device__ __forceinline__ float cross2(float ax, float ay, float bx, float by) {
#pragma clang fp contract(off)
  return ax * by - ay * bx;
}

// Prep: one thread per face, once. SoA edge constants:
// t_k(p) = px*A.x + py*A.y + A.z ; frag = 1/((1+2^t0)(1+2^t1)(1+2^t2)).
// Faces with a repeated vertex INDEX get s=0 exactly (matches numpy's
// exact-zero area -> sign=0 -> frag=1/8 everywhere; dominates the loss).
// Thread 0 also zeroes out[0] (d_out is poisoned 0xAA before every replay);
// loss_kernel runs in a later graph node, so this is race-free.
__global__ void prep_kernel(const float* __restrict__ verts,
                            const int* __restrict__ faces,
                            const float* __restrict__ cam,
                            float4* __restrict__ fd0, float4* __restrict__ fd1,
                            float4* __restrict__ fd2, float* __restrict__ out,
                            int F) {
  int f = blockIdx.x * blockDim.x + threadIdx.x;
  if (f == 0) out[0] = 0.0f;
  if (f >= F) return;
  float ex = cam[0], ey = cam[1], ez = cam[2];
  float zn = sqrtf(ex * ex + ey * ey + ez * ez) + EPSF;
  float izn = frcp(zn);
  float zx = -ex * izn, zy = -ey * izn, zz = -ez * izn;
  float xn = sqrtf(zz * zz + zx * zx) + EPSF;
  float ixn = frcp(xn);
  float xx = zz * ixn, xz = -zx * ixn;           // xy = 0
  float yx = zy * xz;                            // cross(z,x) with xy=0
  float yy = zz * xx - zx * xz;
  float yz = -zy * xx;

  int i0 = faces[3 * f + 0], i1 = faces[3 * f + 1], i2 = faces[3 * f + 2];
  bool deg = (i0 == i1) | (i1 == i2) | (i0 == i2);
  int vi_[3] = {i0, i1, i2};

  float pxs[3], pys[3];
#pragma unroll
  for (int k = 0; k < 3; ++k) {
    int vi = vi_[k];
    float ax = verts[3 * vi + 0] - ex;
    float ay = verts[3 * vi + 1] - ey;
    float az = verts[3 * vi + 2] - ez;
    float vx = ax * xx + az * xz;
    float vy = ax * yx + ay * yy + az * yz;
    float vz = ax * zx + ay * zy + az * zz;
    float izw = frcp(vz * TANV);
    pxs[k] = vx * izw;
    pys[k] = vy * izw;
  }
  float e01x = pxs[1] - pxs[0], e01y = pys[1] - pys[0];
  float e02x = pxs[2] - pxs[0], e02y = pys[2] - pys[0];
  float area = cross2(e01x, e01y, e02x, e02y);
  float s = deg ? 0.0f
                : ((area > 0.0f) ? 1.0f : ((area < 0.0f) ? -1.0f : 0.0f));
  float K = -s * SIGMA_INV * LOG2E;
  float4 o[3];
#pragma unroll
  for (int k = 0; k < 3; ++k) {
    int kn = (k == 2) ? 0 : k + 1;
    float dx = pxs[kn] - pxs[k], dy = pys[kn] - pys[k];
    float il = frcp(sqrtf(dx * dx + dy * dy) + EPSF);
    float nx = -dy * il, ny = dx * il;
    float c = pxs[k] * nx + pys[k] * ny;
    o[k] = make_float4(nx * K, ny * K, -c * K, 0.0f);
  }
  fd0[f] = o[0]; fd1[f] = o[1]; fd2[f] = o[2];
}

// Silhouette partial product. Block = (tile, chunk) from swizzled blockIdx
// (hot tiles are contiguous in tile id; swizzle spreads them over CUs).
// 4 waves x 64 faces cover the 250-face chunk with all lanes active in the
// relevance scan. Phase 2: uniform ctz bit-loop; constants broadcast from
// the scanning lane's registers via v_readlane (no memory). No fences, no
// cross-block coordination (R9's completer+threadfence pattern cost 3x).
__global__ __launch_bounds__(256) void sil_kernel(
    const float4* __restrict__ fd0, const float4* __restrict__ fd1,
    const float4* __restrict__ fd2, float* __restrict__ part,
    int F, int cpf) {
  __shared__ float s_part[NCHUNK * 64];

  int q = (blockIdx.x * 1637) & (NSBLK - 1);   // odd mult: bijection mod 4096
  int tile = q >> 2, chunk = q & 3;
  int tid = threadIdx.x;
  int lane = tid & 63, w = tid >> 6;
  int bx = tile & 31, by = tile >> 5;
  int ix = (bx << 3) + (lane & 7);
  int iy = (by << 3) + (lane >> 3);
  float px = (2.0f * (float)ix + 1.0f) * (1.0f / IMG) - 1.0f;
  float py = 1.0f - (2.0f * (float)iy + 1.0f) * (1.0f / IMG);
  float cx = ((float)(16 * bx + 8)) * (1.0f / IMG) - 1.0f;
  float cy = 1.0f - ((float)(16 * by + 8)) * (1.0f / IMG);
  const float h = 7.0f / IMG;                  // tile half-extent (centers)

  int r = w * 64 + lane;                       // 0..255 within chunk
  int f = chunk * cpf + r;
  int idx = (f < F) ? f : F - 1;               // clamped for safe loads
  float4 a0 = fd0[idx];
  float4 a1 = fd1[idx];
  float4 a2 = fd2[idx];
  // conservative min over tile of t_k; skip face iff some edge >= TSKIP
  float m0 = fmaf(cx, a0.x, fmaf(cy, a0.y, a0.z)) - (fabsf(a0.x) + fabsf(a0.y)) * h;
  float m1 = fmaf(cx, a1.x, fmaf(cy, a1.y, a1.z)) - (fabsf(a1.x) + fabsf(a1.y)) * h;
  float m2 = fmaf(cx, a2.x, fmaf(cy, a2.y, a2.z)) - (fabsf(a2.x) + fabsf(a2.y)) * h;
  bool rel = (r < cpf) && (f < F) && (fmaxf(m0, fmaxf(m1, m2)) < TSKIP);
  unsigned long long mask = __ballot(rel ? 1 : 0);

  float acc = 1.0f;
  while (mask) {
    int j = __builtin_ctzll(mask);
    mask &= mask - 1;
    // broadcast face j's 9 constants from lane j's registers (no memory)
    float b0x = rlane(a0.x, j), b0y = rlane(a0.y, j), b0z = rlane(a0.z, j);
    float b1x = rlane(a1.x, j), b1y = rlane(a1.y, j), b1z = rlane(a1.z, j);
    float b2x = rlane(a2.x, j), b2y = rlane(a2.y, j), b2z = rlane(a2.z, j);
    float t0 = fmaf(px, b0x, fmaf(py, b0y, b0z));
    float t1 = fmaf(px, b1x, fmaf(py, b1y, b1z));
    float t2 = fmaf(px, b2x, fmaf(py, b2y, b2z));
    float D = (1.0f + fexp2(t0)) * (1.0f + fexp2(t1)) * (1.0f + fexp2(t2));
    acc = fmaf(-frcp(D), acc, acc);            // acc *= 1 - 1/D
  }

  s_part[w * 64 + lane] = acc;
  __syncthreads();

  if (w == 0) {
    float p = s_part[lane] * s_part[64 + lane] *
              s_part[128 + lane] * s_part[192 + lane];
    part[chunk * NPIX + iy * IMG + ix] = p;
  }
}

// Combine chunk layers, squared error vs ref, block-reduce, one atomicAdd
// per block into out[0] (zeroed by prep_kernel in an earlier graph node).
__global__ __launch_bounds__(512) void loss_kernel(const float* __restrict__ part,
                                                   const float* __restrict__ ref,
                                                   float* __restrict__ out) {
  int p = blockIdx.x * 512 + threadIdx.x;
  float a = part[p] * part[p + NPIX] * part[p + 2 * NPIX] * part[p + 3 * NPIX];
  float d = (1.0f - a) - ref[p];
  float v = d * d;
#pragma unroll
  for (int off = 32; off > 0; off >>= 1) v += __shfl_down(v, off);
  __shared__ float red[8];
  if ((threadIdx.x & 63) == 0) red[threadIdx.x >> 6] = v;
  __syncthreads();
  if (threadIdx.x == 0) {
    float t = 0.0f;
#pragma unroll
    for (int c = 0; c < 8; ++c) t += red[c];
    atomicAdd(out, t);
  }
}

extern "C" void kernel_launch(void* const* d_in, const int* in_sizes, int n_in,
                              void* d_out, int out_size, void* d_ws, size_t ws_size,
                              hipStream_t stream) {
  const float* verts = (const float*)d_in[0];
  const int* faces = (const int*)d_in[1];
  const float* cam = (const float*)d_in[2];
  const float* imref = (const float*)d_in[3];
  int V = in_sizes[0] / 3;  (void)V;
  int F = in_sizes[1] / 3;  // 1000
  float* out = (float*)d_out;

  char* ws = (char*)d_ws;
  float4* fd0 = (float4*)(ws + 0 * FMAX * 16);
  float4* fd1 = (float4*)(ws + 1 * FMAX * 16);
  float4* fd2 = (float4*)(ws + 2 * FMAX * 16);
  float* part = (float*)(ws + 65536);          // NCHUNK * NPIX floats (1 MB)

  prep_kernel<<<(F + 255) / 256, 256, 0, stream>>>(verts, faces, cam,
                                                   fd0, fd1, fd2, out, F);
  int cpf = (F + NCHUNK - 1) / NCHUNK;         // 250
  sil_kernel<<<NSBLK, 256, 0, stream>>>(fd0, fd1, fd2, part, F, cpf);
  loss_kernel<<<NLBLK, 512, 0, stream>>>(part, imref, out);
}